// Round 1
// baseline (7692.530 us; speedup 1.0000x reference)
//
#include <hip/hip_runtime.h>
#include <math.h>

#define BB 48
#define NN 96
#define EE 1024
#define DD 300
#define LL 4
#define G3 900          // 3*D
#define HDIM 3724       // D*(2L+1)+E
#define ROWS (BB*NN)    // 4608
#define NEGI -1.0e30f

__device__ __forceinline__ float sigm(float x){ return 1.0f/(1.0f+expf(-x)); }

// ---------------- transpose 16 (900,300) weight matrices -> (300,900) ----------------
__global__ void transpose_w(const float* __restrict__ gc_wih, const float* __restrict__ gc_whh,
                            const float* __restrict__ gp_wih, const float* __restrict__ gp_whh,
                            float* __restrict__ wT)
{
    __shared__ float tile[32][33];
    int m = blockIdx.z;            // l*4 + {0:cwi,1:cwh,2:pwi,3:pwh}
    int l = m >> 2; int which = m & 3;
    const float* src = (which==0 ? gc_wih : which==1 ? gc_whh : which==2 ? gp_wih : gp_whh)
                       + (size_t)l*G3*DD;
    float* dst = wT + (size_t)m*DD*G3;
    int g0 = blockIdx.x*32;        // along 900
    int d0 = blockIdx.y*32;        // along 300
    int tx = threadIdx.x, ty = threadIdx.y;   // (32,8)
    #pragma unroll
    for (int r=0;r<32;r+=8){
        int g = g0+ty+r, d = d0+tx;
        tile[ty+r][tx] = (g<G3 && d<DD) ? src[(size_t)g*DD+d] : 0.f;
    }
    __syncthreads();
    #pragma unroll
    for (int r=0;r<32;r+=8){
        int d = d0+ty+r, g = g0+tx;
        if (d<DD && g<G3) dst[(size_t)d*G3+g] = tile[tx][ty+r];
    }
}

// ---------------- generic fp32 GEMM: C = act(A(MxK)*B(KxN) + bias) ----------------
// BM=128, TM=8, BK=16 fixed; 256 threads. M must be a multiple of 128.
template<int BN, int TN>
__global__ __launch_bounds__(256) void gemm_kernel(
    const float* __restrict__ A, int lda,
    const float* __restrict__ B, int ldb,
    const float* __restrict__ bias,
    float* __restrict__ C, int ldc,
    int M, int N, int K, int relu)
{
    constexpr int BM = 128, BK = 16, TM = 8;
    constexpr int NT = BN/TN;                 // 16
    __shared__ float As[BK][BM];
    __shared__ float Bs[BK][BN];
    int tid = threadIdx.x;
    int tx = tid % NT, ty = tid / NT;         // ty 0..15
    int m0 = blockIdx.y * BM;
    int n0 = blockIdx.x * BN;

    float acc[TM][TN];
    #pragma unroll
    for (int r=0;r<TM;r++)
        #pragma unroll
        for (int j=0;j<TN;j++) acc[r][j]=0.f;

    for (int k0=0; k0<K; k0+=BK){
        // stage A tile (BM x BK), transposed into As[k][m]
        #pragma unroll
        for (int it=0; it<2; it++){
            int id = tid + it*256;
            int m = id >> 2, kg = (id & 3) * 4;
            int k = k0 + kg;
            const float* ap = A + (size_t)(m0+m)*lda + k;
            float4 v;
            if (k + 4 <= K){
                v = *(const float4*)ap;
            } else {
                v.x = (k  <K)? ap[0] : 0.f;
                v.y = (k+1<K)? ap[1] : 0.f;
                v.z = (k+2<K)? ap[2] : 0.f;
                v.w = (k+3<K)? ap[3] : 0.f;
            }
            As[kg  ][m]=v.x; As[kg+1][m]=v.y; As[kg+2][m]=v.z; As[kg+3][m]=v.w;
        }
        // stage B tile (BK x BN)
        constexpr int NB4 = (BK*BN/4)/256;    // float4s per thread
        #pragma unroll
        for (int it=0; it<NB4; it++){
            int id = tid + it*256;
            int kr = id / (BN/4);
            int ng = (id % (BN/4)) * 4;
            int k = k0 + kr;
            int n = n0 + ng;
            float4 v = make_float4(0.f,0.f,0.f,0.f);
            if (k < K){
                const float* bp = B + (size_t)k*ldb + n;
                if (n + 4 <= N){
                    v = *(const float4*)bp;
                } else {
                    if (n  <N) v.x = bp[0];
                    if (n+1<N) v.y = bp[1];
                    if (n+2<N) v.z = bp[2];
                    if (n+3<N) v.w = bp[3];
                }
            }
            *(float4*)&Bs[kr][ng] = v;
        }
        __syncthreads();
        #pragma unroll
        for (int kk=0;kk<BK;kk++){
            float a[TM], bfr[TN];
            float4 a0 = *(const float4*)&As[kk][ty*TM];
            float4 a1 = *(const float4*)&As[kk][ty*TM+4];
            a[0]=a0.x;a[1]=a0.y;a[2]=a0.z;a[3]=a0.w;
            a[4]=a1.x;a[5]=a1.y;a[6]=a1.z;a[7]=a1.w;
            #pragma unroll
            for (int j=0;j<TN;j+=4){
                float4 bv = *(const float4*)&Bs[kk][tx*TN+j];
                bfr[j]=bv.x;bfr[j+1]=bv.y;bfr[j+2]=bv.z;bfr[j+3]=bv.w;
            }
            #pragma unroll
            for (int r=0;r<TM;r++)
                #pragma unroll
                for (int j=0;j<TN;j++)
                    acc[r][j] += a[r]*bfr[j];
        }
        __syncthreads();
    }
    #pragma unroll
    for (int r=0;r<TM;r++){
        int m = m0 + ty*TM + r;
        #pragma unroll
        for (int j=0;j<TN;j++){
            int n = n0 + tx*TN + j;
            if (n < N){
                float v = acc[r][j] + bias[n];
                if (relu) v = fmaxf(v, 0.f);
                C[(size_t)m*ldc + n] = v;
            }
        }
    }
}

// ---------------- copy features into last 1024 cols of Hbuf ----------------
__global__ void featcopy(const float* __restrict__ f, float* __restrict__ H)
{
    size_t row = blockIdx.x;
    int t = threadIdx.x;      // 256 threads, one float4 each
    float4 v = *(const float4*)(f + row*EE + t*4);
    *(float4*)(H + row*HDIM + 2700 + t*4) = v;
}

// ---------------- qdot[r] = Cin[r,:]·wq + gb ----------------
__global__ __launch_bounds__(256) void qdot_kernel(
    const float* __restrict__ Hbuf, int ccol,
    const float* __restrict__ wq, const float* __restrict__ gat_b, int l,
    float* __restrict__ qd)
{
    int row = blockIdx.x*4 + (threadIdx.x>>6);
    int lane = threadIdx.x & 63;
    const float* x = Hbuf + (size_t)row*HDIM + ccol;
    float s = 0.f;
    for (int d=lane; d<DD; d+=64) s += x[d]*wq[d];
    #pragma unroll
    for (int o=32;o>0;o>>=1) s += __shfl_down(s,o);
    if (lane==0) qd[row] = s + gat_b[l];
}

// ---------------- the sequential p-scan: one block per batch element ----------------
__global__ __launch_bounds__(1024) void scan_kernel(
    float* __restrict__ Hbuf,
    const float* __restrict__ GHp,     // (4608,900) = Hin@pwh^T + pbh
    const float* __restrict__ pwiT,    // (300,900)
    const float* __restrict__ pwhT,    // (300,900)
    const float* __restrict__ pbi,     // (900)
    const float* __restrict__ pbh,     // (900)
    const float* __restrict__ wk,      // (300)
    const float* __restrict__ qd,      // (4608), includes +gb
    const float* __restrict__ adj,     // (48,96,96)
    float* __restrict__ Mbuf,          // (4608,300)
    int ccol, int hcol, int pcol)
{
    int b = blockIdx.x;
    int t = threadIdx.x;
    __shared__ float alpha_s[NN];
    __shared__ float e_s[NN];
    __shared__ float pk_s[NN];
    __shared__ float M_s[DD];
    __shared__ float g_s[G3];

    size_t rowbase = (size_t)b*NN;

    // ---- init (i=0): p0 = GRU(x=0, h=Cin0), M[b,0]=0
    if (t < DD) M_s[t] = Hbuf[rowbase*HDIM + ccol + t];   // Cin0
    __syncthreads();
    if (t < G3){
        float acc = pbh[t];
        #pragma unroll 4
        for (int d=0; d<DD; d++) acc += M_s[d]*pwhT[(size_t)d*G3+t];
        g_s[t] = acc;                                     // gh0
    }
    __syncthreads();
    if (t < DD){
        float r  = sigm(pbi[t]      + g_s[t]);
        float z  = sigm(pbi[DD+t]   + g_s[DD+t]);
        float nn = tanhf(pbi[2*DD+t] + r*g_s[2*DD+t]);
        float p  = (1.f-z)*nn + z*M_s[t];
        Hbuf[rowbase*HDIM + pcol + t] = p;
        Mbuf[rowbase*DD + t] = 0.f;                        // M[b,0]=0 (for c0)
        g_s[t] = p*wk[t];
    }
    __syncthreads();
    if (t < 64){
        float s=0.f;
        for (int c=t;c<DD;c+=64) s += g_s[c];
        #pragma unroll
        for (int o=32;o>0;o>>=1) s += __shfl_down(s,o);
        if (t==0) pk_s[0]=s;
    }

    for (int i=1;i<NN;i++){
        __syncthreads();   // pk_s[i-1] + P row i-1 ready
        // A: attention logits
        if (t < NN){
            float a = NEGI;
            if (t < i){
                float mk = adj[(rowbase+i)*NN + t];
                if (mk != 0.f) a = qd[rowbase+i] + pk_s[t];
            }
            alpha_s[t] = a;
        }
        __syncthreads();
        // B: softmax weights (wave 0)
        if (t < 64){
            float a0 = alpha_s[t];
            float a1 = (t<32)? alpha_s[64+t] : NEGI;
            float m = fmaxf(a0,a1);
            #pragma unroll
            for (int o=32;o>0;o>>=1) m = fmaxf(m, __shfl_xor(m,o));
            float e0 = expf(a0-m);
            float e1 = (t<32)? expf(a1-m) : 0.f;
            float s = e0+e1;
            #pragma unroll
            for (int o=32;o>0;o>>=1) s += __shfl_xor(s,o);
            float inv = 1.f/s;
            e_s[t] = e0*inv;
            if (t<32) e_s[64+t] = e1*inv;
        }
        __syncthreads();
        // C: M = sum_j w_j * P[b,j,:]
        if (t < DD){
            float acc=0.f;
            const float* Pr = Hbuf + rowbase*HDIM + pcol + t;
            #pragma unroll 4
            for (int j=0;j<i;j++) acc += e_s[j]*Pr[(size_t)j*HDIM];
            M_s[t]=acc;
            Mbuf[(rowbase+i)*DD + t] = acc;
        }
        __syncthreads();
        // D: gip = M @ pwi^T + pbi
        if (t < G3){
            float acc = pbi[t];
            const float* W = pwiT + t;
            #pragma unroll 4
            for (int d=0;d<DD;d++) acc += M_s[d]*W[(size_t)d*G3];
            g_s[t]=acc;
        }
        __syncthreads();
        // E: p_i = GRU combine, write P row, pk terms
        if (t < DD){
            size_t row = rowbase + i;
            const float* gh = GHp + row*G3;
            float r  = sigm(g_s[t]      + gh[t]);
            float z  = sigm(g_s[DD+t]   + gh[DD+t]);
            float nn = tanhf(g_s[2*DD+t] + r*gh[2*DD+t]);
            float hv = Hbuf[row*HDIM + hcol + t];
            float p  = (1.f-z)*nn + z*hv;
            Hbuf[row*HDIM + pcol + t] = p;
            g_s[t] = p*wk[t];
        }
        __syncthreads();
        // F: pk_s[i]
        if (t < 64){
            float s=0.f;
            for (int c=t;c<DD;c+=64) s += g_s[c];
            #pragma unroll
            for (int o=32;o>0;o>>=1) s += __shfl_down(s,o);
            if (t==0) pk_s[i]=s;
        }
    }
}

// ---------------- c-side elementwise combine: CL = GRU(GIc, GHc, h=M) ----------------
__global__ __launch_bounds__(320) void combine_c(
    const float* __restrict__ GIc, const float* __restrict__ GHc,
    const float* __restrict__ Mbuf, float* __restrict__ Hbuf, int clcol)
{
    size_t row = blockIdx.x;
    int d = threadIdx.x;
    if (d < DD){
        float ir = GIc[row*G3+d], iz = GIc[row*G3+DD+d], inn = GIc[row*G3+2*DD+d];
        float hr = GHc[row*G3+d], hz = GHc[row*G3+DD+d], hn  = GHc[row*G3+2*DD+d];
        float r  = sigm(ir+hr);
        float z  = sigm(iz+hz);
        float nn = tanhf(inn + r*hn);
        float h  = Mbuf[row*DD+d];
        Hbuf[row*HDIM + clcol + d] = (1.f-z)*nn + z*h;
    }
}

// ---------------- logits: out = x2 @ w2 + b2 (N=7) ----------------
__global__ __launch_bounds__(64) void logits_kernel(
    const float* __restrict__ x2, const float* __restrict__ w2,
    const float* __restrict__ b2, float* __restrict__ out)
{
    size_t row = blockIdx.x;
    int lane = threadIdx.x;
    float acc[7]={0,0,0,0,0,0,0};
    for (int d=lane; d<DD; d+=64){
        float x = x2[row*DD+d];
        #pragma unroll
        for (int c=0;c<7;c++) acc[c] += x*w2[d*7+c];
    }
    #pragma unroll
    for (int c=0;c<7;c++){
        float s = acc[c];
        #pragma unroll
        for (int o=32;o>0;o>>=1) s += __shfl_down(s,o);
        if (lane==0) out[row*7+c] = s + b2[c];
    }
}

extern "C" void kernel_launch(void* const* d_in, const int* in_sizes, int n_in,
                              void* d_out, int out_size, void* d_ws, size_t ws_size,
                              hipStream_t stream)
{
    const float* features = (const float*)d_in[0];
    const float* adj      = (const float*)d_in[1];
    // d_in[2] s_mask: unused by reference
    const float* fc1_w    = (const float*)d_in[3];
    const float* fc1_b    = (const float*)d_in[4];
    const float* gc_wih   = (const float*)d_in[5];
    const float* gc_whh   = (const float*)d_in[6];
    const float* gc_bih   = (const float*)d_in[7];
    const float* gc_bhh   = (const float*)d_in[8];
    const float* gp_wih   = (const float*)d_in[9];
    const float* gp_whh   = (const float*)d_in[10];
    const float* gp_bih   = (const float*)d_in[11];
    const float* gp_bhh   = (const float*)d_in[12];
    const float* gat_wq   = (const float*)d_in[13];
    const float* gat_wk   = (const float*)d_in[14];
    const float* gat_b    = (const float*)d_in[15];
    const float* mlp_w0   = (const float*)d_in[16];
    const float* mlp_b0   = (const float*)d_in[17];
    const float* mlp_w1   = (const float*)d_in[18];
    const float* mlp_b1   = (const float*)d_in[19];
    const float* mlp_w2   = (const float*)d_in[20];
    const float* mlp_b2   = (const float*)d_in[21];
    float* out = (float*)d_out;

    float* ws = (float*)d_ws;
    size_t off = 0;
    float* Hbuf = ws + off; off += (size_t)ROWS*HDIM;  // 17,160,192
    float* bufA = ws + off; off += (size_t)ROWS*G3;    // GHp
    float* bufB = ws + off; off += (size_t)ROWS*G3;    // GIc / x1
    float* bufC = ws + off; off += (size_t)ROWS*G3;    // GHc / x2
    float* Mbuf = ws + off; off += (size_t)ROWS*DD;
    float* qd   = ws + off; off += ROWS;
    float* wT   = ws + off; off += (size_t)16*DD*G3;
    (void)ws_size; (void)in_sizes; (void)n_in; (void)out_size;

    // 1. transpose all GRU weights once
    {
        dim3 g((G3+31)/32, (DD+31)/32, 16);
        dim3 bl(32,8);
        transpose_w<<<g, bl, 0, stream>>>(gc_wih, gc_whh, gp_wih, gp_whh, wT);
    }
    // 2. H0 = relu(features @ fc1_w + fc1_b) -> Hbuf col 0
    gemm_kernel<64,4><<<dim3(5,36),256,0,stream>>>(features, EE, fc1_w, DD, fc1_b,
                                                   Hbuf, HDIM, ROWS, DD, EE, 1);
    // 3. features -> Hbuf cols [2700,3724)
    featcopy<<<ROWS,256,0,stream>>>(features, Hbuf);

    for (int l=0;l<LL;l++){
        int ccol  = (l==0)? 0 : 300 + (l-1)*600;  // Cin(l)
        int hcol  = l*300;                         // Hin(l)
        int pcol  = 600 + l*600;                   // P(l) slot
        int clcol = 300 + l*600;                   // CL(l) slot
        const float* cwiT = wT + (size_t)(l*4+0)*DD*G3;
        const float* cwhT = wT + (size_t)(l*4+1)*DD*G3;
        const float* pwiT = wT + (size_t)(l*4+2)*DD*G3;
        const float* pwhT = wT + (size_t)(l*4+3)*DD*G3;

        // GHp = Hin @ pwh^T + pbh
        gemm_kernel<128,8><<<dim3(8,36),256,0,stream>>>(Hbuf+hcol, HDIM, pwhT, G3,
                                                        gp_bhh + l*G3, bufA, G3,
                                                        ROWS, G3, DD, 0);
        // qdot = Cin·wq + gb
        qdot_kernel<<<1152,256,0,stream>>>(Hbuf, ccol, gat_wq + l*DD, gat_b, l, qd);
        // sequential p-scan (stores P rows into Hbuf, M into Mbuf)
        scan_kernel<<<BB,1024,0,stream>>>(Hbuf, bufA, pwiT, pwhT,
                                          gp_bih + l*G3, gp_bhh + l*G3,
                                          gat_wk + l*DD, qd, adj, Mbuf,
                                          ccol, hcol, pcol);
        // GIc = Cin @ cwi^T + cbi
        gemm_kernel<128,8><<<dim3(8,36),256,0,stream>>>(Hbuf+ccol, HDIM, cwiT, G3,
                                                        gc_bih + l*G3, bufB, G3,
                                                        ROWS, G3, DD, 0);
        // GHc = M @ cwh^T + cbh
        gemm_kernel<128,8><<<dim3(8,36),256,0,stream>>>(Mbuf, DD, cwhT, G3,
                                                        gc_bhh + l*G3, bufC, G3,
                                                        ROWS, G3, DD, 0);
        // CL = GRU-combine -> Hbuf clcol (becomes Cin of next layer)
        combine_c<<<ROWS,320,0,stream>>>(bufB, bufC, Mbuf, Hbuf, clcol);
    }

    // MLP
    gemm_kernel<64,4><<<dim3(5,36),256,0,stream>>>(Hbuf, HDIM, mlp_w0, DD, mlp_b0,
                                                   bufB, DD, ROWS, DD, HDIM, 1);
    gemm_kernel<64,4><<<dim3(5,36),256,0,stream>>>(bufB, DD, mlp_w1, DD, mlp_b1,
                                                   bufC, DD, ROWS, DD, DD, 1);
    logits_kernel<<<ROWS,64,0,stream>>>(bufC, mlp_w2, mlp_b2, out);
}

// Round 2
// 5967.183 us; speedup vs baseline: 1.2891x; 1.2891x over previous
//
#include <hip/hip_runtime.h>
#include <math.h>

#define BB 48
#define NN 96
#define EE 1024
#define DD 300
#define LL 4
#define G3 900          // 3*D
#define PP 150          // DD/2 packed bf16 pairs
#define HDIM 3724       // D*(2L+1)+E
#define ROWS (BB*NN)    // 4608
#define NEGI -1.0e30f

__device__ __forceinline__ float sigm(float x){ return 1.0f/(1.0f+expf(-x)); }

__device__ __forceinline__ unsigned f2bf(float x){
    unsigned u = __float_as_uint(x);
    return (u + 0x7fffu + ((u>>16)&1u)) >> 16;   // RNE
}

// ---------------- transpose 16 (900,300) weight matrices -> (300,900) ----------------
__global__ void transpose_w(const float* __restrict__ gc_wih, const float* __restrict__ gc_whh,
                            const float* __restrict__ gp_wih, const float* __restrict__ gp_whh,
                            float* __restrict__ wT)
{
    __shared__ float tile[32][33];
    int m = blockIdx.z;            // l*4 + {0:cwi,1:cwh,2:pwi,3:pwh}
    int l = m >> 2; int which = m & 3;
    const float* src = (which==0 ? gc_wih : which==1 ? gc_whh : which==2 ? gp_wih : gp_whh)
                       + (size_t)l*G3*DD;
    float* dst = wT + (size_t)m*DD*G3;
    int g0 = blockIdx.x*32;        // along 900
    int d0 = blockIdx.y*32;        // along 300
    int tx = threadIdx.x, ty = threadIdx.y;   // (32,8)
    #pragma unroll
    for (int r=0;r<32;r+=8){
        int g = g0+ty+r, d = d0+tx;
        tile[ty+r][tx] = (g<G3 && d<DD) ? src[(size_t)g*DD+d] : 0.f;
    }
    __syncthreads();
    #pragma unroll
    for (int r=0;r<32;r+=8){
        int d = d0+ty+r, g = g0+tx;
        if (d<DD && g<G3) dst[(size_t)d*G3+g] = tile[tx][ty+r];
    }
}

// ---------------- pack pwi (L,900,300) -> bf16-pair layout (L,150,900) ----------------
// pwiP[l][p*G3+g] = bf16(W[g][2p]) | bf16(W[g][2p+1])<<16
__global__ __launch_bounds__(256) void pack_pwi(const float* __restrict__ gp_wih,
                                                unsigned* __restrict__ pwiP)
{
    int l = blockIdx.y;
    int idx = blockIdx.x*256 + threadIdx.x;
    if (idx >= PP*G3) return;
    int p = idx / G3, g = idx % G3;
    const float* src = gp_wih + (size_t)l*G3*DD + (size_t)g*DD + 2*p;
    unsigned a = f2bf(src[0]);
    unsigned b = f2bf(src[1]);
    pwiP[(size_t)l*PP*G3 + idx] = a | (b<<16);
}

// ---------------- generic fp32 GEMM: C = act(A(MxK)*B(KxN) + bias) ----------------
template<int BN, int TN>
__global__ __launch_bounds__(256) void gemm_kernel(
    const float* __restrict__ A, int lda,
    const float* __restrict__ B, int ldb,
    const float* __restrict__ bias,
    float* __restrict__ C, int ldc,
    int M, int N, int K, int relu)
{
    constexpr int BM = 128, BK = 16, TM = 8;
    constexpr int NT = BN/TN;                 // 16
    __shared__ float As[BK][BM];
    __shared__ float Bs[BK][BN];
    int tid = threadIdx.x;
    int tx = tid % NT, ty = tid / NT;
    int m0 = blockIdx.y * BM;
    int n0 = blockIdx.x * BN;

    float acc[TM][TN];
    #pragma unroll
    for (int r=0;r<TM;r++)
        #pragma unroll
        for (int j=0;j<TN;j++) acc[r][j]=0.f;

    for (int k0=0; k0<K; k0+=BK){
        #pragma unroll
        for (int it=0; it<2; it++){
            int id = tid + it*256;
            int m = id >> 2, kg = (id & 3) * 4;
            int k = k0 + kg;
            const float* ap = A + (size_t)(m0+m)*lda + k;
            float4 v;
            if (k + 4 <= K){
                v = *(const float4*)ap;
            } else {
                v.x = (k  <K)? ap[0] : 0.f;
                v.y = (k+1<K)? ap[1] : 0.f;
                v.z = (k+2<K)? ap[2] : 0.f;
                v.w = (k+3<K)? ap[3] : 0.f;
            }
            As[kg  ][m]=v.x; As[kg+1][m]=v.y; As[kg+2][m]=v.z; As[kg+3][m]=v.w;
        }
        constexpr int NB4 = (BK*BN/4)/256;
        #pragma unroll
        for (int it=0; it<NB4; it++){
            int id = tid + it*256;
            int kr = id / (BN/4);
            int ng = (id % (BN/4)) * 4;
            int k = k0 + kr;
            int n = n0 + ng;
            float4 v = make_float4(0.f,0.f,0.f,0.f);
            if (k < K){
                const float* bp = B + (size_t)k*ldb + n;
                if (n + 4 <= N){
                    v = *(const float4*)bp;
                } else {
                    if (n  <N) v.x = bp[0];
                    if (n+1<N) v.y = bp[1];
                    if (n+2<N) v.z = bp[2];
                    if (n+3<N) v.w = bp[3];
                }
            }
            *(float4*)&Bs[kr][ng] = v;
        }
        __syncthreads();
        #pragma unroll
        for (int kk=0;kk<BK;kk++){
            float a[TM], bfr[TN];
            float4 a0 = *(const float4*)&As[kk][ty*TM];
            float4 a1 = *(const float4*)&As[kk][ty*TM+4];
            a[0]=a0.x;a[1]=a0.y;a[2]=a0.z;a[3]=a0.w;
            a[4]=a1.x;a[5]=a1.y;a[6]=a1.z;a[7]=a1.w;
            #pragma unroll
            for (int j=0;j<TN;j+=4){
                float4 bv = *(const float4*)&Bs[kk][tx*TN+j];
                bfr[j]=bv.x;bfr[j+1]=bv.y;bfr[j+2]=bv.z;bfr[j+3]=bv.w;
            }
            #pragma unroll
            for (int r=0;r<TM;r++)
                #pragma unroll
                for (int j=0;j<TN;j++)
                    acc[r][j] += a[r]*bfr[j];
        }
        __syncthreads();
    }
    #pragma unroll
    for (int r=0;r<TM;r++){
        int m = m0 + ty*TM + r;
        #pragma unroll
        for (int j=0;j<TN;j++){
            int n = n0 + tx*TN + j;
            if (n < N){
                float v = acc[r][j] + bias[n];
                if (relu) v = fmaxf(v, 0.f);
                C[(size_t)m*ldc + n] = v;
            }
        }
    }
}

// ---------------- copy features into last 1024 cols of Hbuf ----------------
__global__ void featcopy(const float* __restrict__ f, float* __restrict__ H)
{
    size_t row = blockIdx.x;
    int t = threadIdx.x;
    float4 v = *(const float4*)(f + row*EE + t*4);
    *(float4*)(H + row*HDIM + 2700 + t*4) = v;
}

// ---------------- qdot[r] = Cin[r,:]·wq + gb ----------------
__global__ __launch_bounds__(256) void qdot_kernel(
    const float* __restrict__ Hbuf, int ccol,
    const float* __restrict__ wq, const float* __restrict__ gat_b, int l,
    float* __restrict__ qd)
{
    int row = blockIdx.x*4 + (threadIdx.x>>6);
    int lane = threadIdx.x & 63;
    const float* x = Hbuf + (size_t)row*HDIM + ccol;
    float s = 0.f;
    for (int d=lane; d<DD; d+=64) s += x[d]*wq[d];
    #pragma unroll
    for (int o=32;o>0;o>>=1) s += __shfl_down(s,o);
    if (lane==0) qd[row] = s + gat_b[l];
}

// ---------------- the sequential p-scan: one block per batch element ----------------
__global__ __launch_bounds__(1024) void scan_kernel(
    float* __restrict__ Hbuf,
    const float* __restrict__ GHp,     // (4608,900) = Hin@pwh^T + pbh
    const unsigned* __restrict__ pwiP, // (150,900) bf16 pairs
    const float* __restrict__ pwhT,    // (300,900) fp32 (init only)
    const float* __restrict__ pbi,     // (900)
    const float* __restrict__ pbh,     // (900)
    const float* __restrict__ wk,      // (300)
    const float* __restrict__ qd,      // (4608), includes +gb
    const float* __restrict__ adj,     // (48,96,96)
    float* __restrict__ Mbuf,          // (4608,300)
    int ccol, int hcol, int pcol)
{
    int b = blockIdx.x;
    int t = threadIdx.x;
    __shared__ float alpha_s[NN];
    __shared__ float e_s[NN];
    __shared__ float pk_s[NN];
    __shared__ float M_s[DD];
    __shared__ float g_s[G3];

    size_t rowbase = (size_t)b*NN;

    // ---- init (i=0): p0 = GRU(x=0, h=Cin0), M[b,0]=0
    if (t < DD) M_s[t] = Hbuf[rowbase*HDIM + ccol + t];   // Cin0
    __syncthreads();
    if (t < G3){
        float acc = pbh[t];
        #pragma unroll 4
        for (int d=0; d<DD; d++) acc += M_s[d]*pwhT[(size_t)d*G3+t];
        g_s[t] = acc;                                     // gh0
    }
    __syncthreads();
    if (t < DD){
        float r  = sigm(pbi[t]      + g_s[t]);
        float z  = sigm(pbi[DD+t]   + g_s[DD+t]);
        float nn = tanhf(pbi[2*DD+t] + r*g_s[2*DD+t]);
        float p  = (1.f-z)*nn + z*M_s[t];
        Hbuf[rowbase*HDIM + pcol + t] = p;
        Mbuf[rowbase*DD + t] = 0.f;                        // M[b,0]=0 (for c0)
        g_s[t] = p*wk[t];
    }
    __syncthreads();
    if (t < 64){
        float s=0.f;
        for (int c=t;c<DD;c+=64) s += g_s[c];
        #pragma unroll
        for (int o=32;o>0;o>>=1) s += __shfl_down(s,o);
        if (t==0) pk_s[0]=s;
    }

    for (int i=1;i<NN;i++){
        __syncthreads();   // pk_s[i-1] + P row i-1 ready
        // A: attention logits
        if (t < NN){
            float a = NEGI;
            if (t < i){
                float mk = adj[(rowbase+i)*NN + t];
                if (mk != 0.f) a = qd[rowbase+i] + pk_s[t];
            }
            alpha_s[t] = a;
        }
        __syncthreads();
        // B: softmax weights (wave 0)
        if (t < 64){
            float a0 = alpha_s[t];
            float a1 = (t<32)? alpha_s[64+t] : NEGI;
            float m = fmaxf(a0,a1);
            #pragma unroll
            for (int o=32;o>0;o>>=1) m = fmaxf(m, __shfl_xor(m,o));
            float e0 = expf(a0-m);
            float e1 = (t<32)? expf(a1-m) : 0.f;
            float s = e0+e1;
            #pragma unroll
            for (int o=32;o>0;o>>=1) s += __shfl_xor(s,o);
            float inv = 1.f/s;
            e_s[t] = e0*inv;
            if (t<32) e_s[64+t] = e1*inv;
        }
        __syncthreads();
        // C: M = sum_j w_j * P[b,j,:]
        if (t < DD){
            float acc=0.f;
            const float* Pr = Hbuf + rowbase*HDIM + pcol + t;
            #pragma unroll 4
            for (int j=0;j<i;j++) acc += e_s[j]*Pr[(size_t)j*HDIM];
            M_s[t]=acc;
            Mbuf[(rowbase+i)*DD + t] = acc;
        }
        __syncthreads();
        // D: gip = M @ pwi^T + pbi  -- bf16-pair packed weight stream
        if (t < G3){
            float acc0 = 0.f, acc1 = 0.f;
            const unsigned* W = pwiP + t;
            #pragma unroll 10
            for (int p=0;p<PP;p++){
                unsigned w2 = W[(size_t)p*G3];
                acc0 += M_s[2*p]   * __uint_as_float(w2<<16);
                acc1 += M_s[2*p+1] * __uint_as_float(w2 & 0xffff0000u);
            }
            g_s[t] = pbi[t] + acc0 + acc1;
        }
        __syncthreads();
        // E: p_i = GRU combine, write P row, pk terms
        if (t < DD){
            size_t row = rowbase + i;
            const float* gh = GHp + row*G3;
            float r  = sigm(g_s[t]      + gh[t]);
            float z  = sigm(g_s[DD+t]   + gh[DD+t]);
            float nn = tanhf(g_s[2*DD+t] + r*gh[2*DD+t]);
            float hv = Hbuf[row*HDIM + hcol + t];
            float p  = (1.f-z)*nn + z*hv;
            Hbuf[row*HDIM + pcol + t] = p;
            g_s[t] = p*wk[t];
        }
        __syncthreads();
        // F: pk_s[i]
        if (t < 64){
            float s=0.f;
            for (int c=t;c<DD;c+=64) s += g_s[c];
            #pragma unroll
            for (int o=32;o>0;o>>=1) s += __shfl_down(s,o);
            if (t==0) pk_s[i]=s;
        }
    }
}

// ---------------- c-side elementwise combine: CL = GRU(GIc, GHc, h=M) ----------------
__global__ __launch_bounds__(320) void combine_c(
    const float* __restrict__ GIc, const float* __restrict__ GHc,
    const float* __restrict__ Mbuf, float* __restrict__ Hbuf, int clcol)
{
    size_t row = blockIdx.x;
    int d = threadIdx.x;
    if (d < DD){
        float ir = GIc[row*G3+d], iz = GIc[row*G3+DD+d], inn = GIc[row*G3+2*DD+d];
        float hr = GHc[row*G3+d], hz = GHc[row*G3+DD+d], hn  = GHc[row*G3+2*DD+d];
        float r  = sigm(ir+hr);
        float z  = sigm(iz+hz);
        float nn = tanhf(inn + r*hn);
        float h  = Mbuf[row*DD+d];
        Hbuf[row*HDIM + clcol + d] = (1.f-z)*nn + z*h;
    }
}

// ---------------- logits: out = x2 @ w2 + b2 (N=7) ----------------
__global__ __launch_bounds__(64) void logits_kernel(
    const float* __restrict__ x2, const float* __restrict__ w2,
    const float* __restrict__ b2, float* __restrict__ out)
{
    size_t row = blockIdx.x;
    int lane = threadIdx.x;
    float acc[7]={0,0,0,0,0,0,0};
    for (int d=lane; d<DD; d+=64){
        float x = x2[row*DD+d];
        #pragma unroll
        for (int c=0;c<7;c++) acc[c] += x*w2[d*7+c];
    }
    #pragma unroll
    for (int c=0;c<7;c++){
        float s = acc[c];
        #pragma unroll
        for (int o=32;o>0;o>>=1) s += __shfl_down(s,o);
        if (lane==0) out[row*7+c] = s + b2[c];
    }
}

extern "C" void kernel_launch(void* const* d_in, const int* in_sizes, int n_in,
                              void* d_out, int out_size, void* d_ws, size_t ws_size,
                              hipStream_t stream)
{
    const float* features = (const float*)d_in[0];
    const float* adj      = (const float*)d_in[1];
    const float* fc1_w    = (const float*)d_in[3];
    const float* fc1_b    = (const float*)d_in[4];
    const float* gc_wih   = (const float*)d_in[5];
    const float* gc_whh   = (const float*)d_in[6];
    const float* gc_bih   = (const float*)d_in[7];
    const float* gc_bhh   = (const float*)d_in[8];
    const float* gp_wih   = (const float*)d_in[9];
    const float* gp_whh   = (const float*)d_in[10];
    const float* gp_bih   = (const float*)d_in[11];
    const float* gp_bhh   = (const float*)d_in[12];
    const float* gat_wq   = (const float*)d_in[13];
    const float* gat_wk   = (const float*)d_in[14];
    const float* gat_b    = (const float*)d_in[15];
    const float* mlp_w0   = (const float*)d_in[16];
    const float* mlp_b0   = (const float*)d_in[17];
    const float* mlp_w1   = (const float*)d_in[18];
    const float* mlp_b1   = (const float*)d_in[19];
    const float* mlp_w2   = (const float*)d_in[20];
    const float* mlp_b2   = (const float*)d_in[21];
    float* out = (float*)d_out;

    float* ws = (float*)d_ws;
    size_t off = 0;
    float* Hbuf = ws + off; off += (size_t)ROWS*HDIM;
    float* bufA = ws + off; off += (size_t)ROWS*G3;    // GHp
    float* bufB = ws + off; off += (size_t)ROWS*G3;    // GIc / x1
    float* bufC = ws + off; off += (size_t)ROWS*G3;    // GHc / x2
    float* Mbuf = ws + off; off += (size_t)ROWS*DD;
    float* qd   = ws + off; off += ROWS;
    float* wT   = ws + off; off += (size_t)16*DD*G3;
    unsigned* pwiP = (unsigned*)(ws + off); off += (size_t)LL*PP*G3;
    (void)ws_size; (void)in_sizes; (void)n_in; (void)out_size;

    // 1. transpose GRU weights (fp32) + pack pwi to bf16 pairs
    {
        dim3 g((G3+31)/32, (DD+31)/32, 16);
        dim3 bl(32,8);
        transpose_w<<<g, bl, 0, stream>>>(gc_wih, gc_whh, gp_wih, gp_whh, wT);
        pack_pwi<<<dim3((PP*G3+255)/256, LL), 256, 0, stream>>>(gp_wih, pwiP);
    }
    // 2. H0 = relu(features @ fc1_w + fc1_b) -> Hbuf col 0
    gemm_kernel<64,4><<<dim3(5,36),256,0,stream>>>(features, EE, fc1_w, DD, fc1_b,
                                                   Hbuf, HDIM, ROWS, DD, EE, 1);
    // 3. features -> Hbuf cols [2700,3724)
    featcopy<<<ROWS,256,0,stream>>>(features, Hbuf);

    for (int l=0;l<LL;l++){
        int ccol  = (l==0)? 0 : 300 + (l-1)*600;
        int hcol  = l*300;
        int pcol  = 600 + l*600;
        int clcol = 300 + l*600;
        const float* cwiT = wT + (size_t)(l*4+0)*DD*G3;
        const float* cwhT = wT + (size_t)(l*4+1)*DD*G3;
        const float* pwhT = wT + (size_t)(l*4+3)*DD*G3;
        const unsigned* pwiPl = pwiP + (size_t)l*PP*G3;

        // GHp = Hin @ pwh^T + pbh
        gemm_kernel<128,8><<<dim3(8,36),256,0,stream>>>(Hbuf+hcol, HDIM, pwhT, G3,
                                                        gp_bhh + l*G3, bufA, G3,
                                                        ROWS, G3, DD, 0);
        // qdot = Cin·wq + gb
        qdot_kernel<<<1152,256,0,stream>>>(Hbuf, ccol, gat_wq + l*DD, gat_b, l, qd);
        // sequential p-scan
        scan_kernel<<<BB,1024,0,stream>>>(Hbuf, bufA, pwiPl, pwhT,
                                          gp_bih + l*G3, gp_bhh + l*G3,
                                          gat_wk + l*DD, qd, adj, Mbuf,
                                          ccol, hcol, pcol);
        // GIc = Cin @ cwi^T + cbi
        gemm_kernel<128,8><<<dim3(8,36),256,0,stream>>>(Hbuf+ccol, HDIM, cwiT, G3,
                                                        gc_bih + l*G3, bufB, G3,
                                                        ROWS, G3, DD, 0);
        // GHc = M @ cwh^T + cbh
        gemm_kernel<128,8><<<dim3(8,36),256,0,stream>>>(Mbuf, DD, cwhT, G3,
                                                        gc_bhh + l*G3, bufC, G3,
                                                        ROWS, G3, DD, 0);
        // CL = GRU-combine
        combine_c<<<ROWS,320,0,stream>>>(bufB, bufC, Mbuf, Hbuf, clcol);
    }

    // MLP
    gemm_kernel<64,4><<<dim3(5,36),256,0,stream>>>(Hbuf, HDIM, mlp_w0, DD, mlp_b0,
                                                   bufB, DD, ROWS, DD, HDIM, 1);
    gemm_kernel<64,4><<<dim3(5,36),256,0,stream>>>(bufB, DD, mlp_w1, DD, mlp_b1,
                                                   bufC, DD, ROWS, DD, DD, 1);
    logits_kernel<<<ROWS,64,0,stream>>>(bufC, mlp_w2, mlp_b2, out);
}

// Round 3
// 5024.361 us; speedup vs baseline: 1.5310x; 1.1877x over previous
//
#include <hip/hip_runtime.h>
#include <math.h>

#define BB 48
#define NN 96
#define EE 1024
#define DD 300
#define LL 4
#define G3 900          // 3*D
#define PP 150          // DD/2 packed f16 pairs
#define HDIM 3724       // D*(2L+1)+E
#define ROWS (BB*NN)    // 4608
#define NEGI -1.0e30f

typedef _Float16 half2_t __attribute__((ext_vector_type(2)));

__device__ __forceinline__ float sigm(float x){ return 1.0f/(1.0f+expf(-x)); }

// ---------------- transpose 16 (900,300) weight matrices -> (300,900) ----------------
__global__ void transpose_w(const float* __restrict__ gc_wih, const float* __restrict__ gc_whh,
                            const float* __restrict__ gp_wih, const float* __restrict__ gp_whh,
                            float* __restrict__ wT)
{
    __shared__ float tile[32][33];
    int m = blockIdx.z;            // l*4 + {0:cwi,1:cwh,2:pwi,3:pwh}
    int l = m >> 2; int which = m & 3;
    const float* src = (which==0 ? gc_wih : which==1 ? gc_whh : which==2 ? gp_wih : gp_whh)
                       + (size_t)l*G3*DD;
    float* dst = wT + (size_t)m*DD*G3;
    int g0 = blockIdx.x*32;        // along 900
    int d0 = blockIdx.y*32;        // along 300
    int tx = threadIdx.x, ty = threadIdx.y;   // (32,8)
    #pragma unroll
    for (int r=0;r<32;r+=8){
        int g = g0+ty+r, d = d0+tx;
        tile[ty+r][tx] = (g<G3 && d<DD) ? src[(size_t)g*DD+d] : 0.f;
    }
    __syncthreads();
    #pragma unroll
    for (int r=0;r<32;r+=8){
        int d = d0+ty+r, g = g0+tx;
        if (d<DD && g<G3) dst[(size_t)d*G3+g] = tile[tx][ty+r];
    }
}

// ---------------- pack pwi (L,900,300) -> f16-pair layout (L,150,900) ----------------
// pwiH[l][p*G3+g] = (f16(W[g][2p]), f16(W[g][2p+1]))
__global__ __launch_bounds__(256) void pack_pwi(const float* __restrict__ gp_wih,
                                                half2_t* __restrict__ pwiH)
{
    int l = blockIdx.y;
    int idx = blockIdx.x*256 + threadIdx.x;
    if (idx >= PP*G3) return;
    int p = idx / G3, g = idx % G3;
    const float* src = gp_wih + (size_t)l*G3*DD + (size_t)g*DD + 2*p;
    half2_t h;
    h.x = (_Float16)src[0];
    h.y = (_Float16)src[1];
    pwiH[(size_t)l*PP*G3 + idx] = h;
}

// ---------------- generic fp32 GEMM: C = act(A(MxK)*B(KxN) + bias) ----------------
template<int BN, int TN>
__global__ __launch_bounds__(256) void gemm_kernel(
    const float* __restrict__ A, int lda,
    const float* __restrict__ B, int ldb,
    const float* __restrict__ bias,
    float* __restrict__ C, int ldc,
    int M, int N, int K, int relu)
{
    constexpr int BM = 128, BK = 16, TM = 8;
    constexpr int NT = BN/TN;                 // 16
    __shared__ float As[BK][BM];
    __shared__ float Bs[BK][BN];
    int tid = threadIdx.x;
    int tx = tid % NT, ty = tid / NT;
    int m0 = blockIdx.y * BM;
    int n0 = blockIdx.x * BN;

    float acc[TM][TN];
    #pragma unroll
    for (int r=0;r<TM;r++)
        #pragma unroll
        for (int j=0;j<TN;j++) acc[r][j]=0.f;

    for (int k0=0; k0<K; k0+=BK){
        #pragma unroll
        for (int it=0; it<2; it++){
            int id = tid + it*256;
            int m = id >> 2, kg = (id & 3) * 4;
            int k = k0 + kg;
            const float* ap = A + (size_t)(m0+m)*lda + k;
            float4 v;
            if (k + 4 <= K){
                v = *(const float4*)ap;
            } else {
                v.x = (k  <K)? ap[0] : 0.f;
                v.y = (k+1<K)? ap[1] : 0.f;
                v.z = (k+2<K)? ap[2] : 0.f;
                v.w = (k+3<K)? ap[3] : 0.f;
            }
            As[kg  ][m]=v.x; As[kg+1][m]=v.y; As[kg+2][m]=v.z; As[kg+3][m]=v.w;
        }
        constexpr int NB4 = (BK*BN/4)/256;
        #pragma unroll
        for (int it=0; it<NB4; it++){
            int id = tid + it*256;
            int kr = id / (BN/4);
            int ng = (id % (BN/4)) * 4;
            int k = k0 + kr;
            int n = n0 + ng;
            float4 v = make_float4(0.f,0.f,0.f,0.f);
            if (k < K){
                const float* bp = B + (size_t)k*ldb + n;
                if (n + 4 <= N){
                    v = *(const float4*)bp;
                } else {
                    if (n  <N) v.x = bp[0];
                    if (n+1<N) v.y = bp[1];
                    if (n+2<N) v.z = bp[2];
                    if (n+3<N) v.w = bp[3];
                }
            }
            *(float4*)&Bs[kr][ng] = v;
        }
        __syncthreads();
        #pragma unroll
        for (int kk=0;kk<BK;kk++){
            float a[TM], bfr[TN];
            float4 a0 = *(const float4*)&As[kk][ty*TM];
            float4 a1 = *(const float4*)&As[kk][ty*TM+4];
            a[0]=a0.x;a[1]=a0.y;a[2]=a0.z;a[3]=a0.w;
            a[4]=a1.x;a[5]=a1.y;a[6]=a1.z;a[7]=a1.w;
            #pragma unroll
            for (int j=0;j<TN;j+=4){
                float4 bv = *(const float4*)&Bs[kk][tx*TN+j];
                bfr[j]=bv.x;bfr[j+1]=bv.y;bfr[j+2]=bv.z;bfr[j+3]=bv.w;
            }
            #pragma unroll
            for (int r=0;r<TM;r++)
                #pragma unroll
                for (int j=0;j<TN;j++)
                    acc[r][j] += a[r]*bfr[j];
        }
        __syncthreads();
    }
    #pragma unroll
    for (int r=0;r<TM;r++){
        int m = m0 + ty*TM + r;
        #pragma unroll
        for (int j=0;j<TN;j++){
            int n = n0 + tx*TN + j;
            if (n < N){
                float v = acc[r][j] + bias[n];
                if (relu) v = fmaxf(v, 0.f);
                C[(size_t)m*ldc + n] = v;
            }
        }
    }
}

// ---------------- copy features into last 1024 cols of Hbuf ----------------
__global__ void featcopy(const float* __restrict__ f, float* __restrict__ H)
{
    size_t row = blockIdx.x;
    int t = threadIdx.x;
    float4 v = *(const float4*)(f + row*EE + t*4);
    *(float4*)(H + row*HDIM + 2700 + t*4) = v;
}

// ---------------- qdot[r] = Cin[r,:]·wq + gb ----------------
__global__ __launch_bounds__(256) void qdot_kernel(
    const float* __restrict__ Hbuf, int ccol,
    const float* __restrict__ wq, const float* __restrict__ gat_b, int l,
    float* __restrict__ qd)
{
    int row = blockIdx.x*4 + (threadIdx.x>>6);
    int lane = threadIdx.x & 63;
    const float* x = Hbuf + (size_t)row*HDIM + ccol;
    float s = 0.f;
    for (int d=lane; d<DD; d+=64) s += x[d]*wq[d];
    #pragma unroll
    for (int o=32;o>0;o>>=1) s += __shfl_down(s,o);
    if (lane==0) qd[row] = s + gat_b[l];
}

// ---------------- the sequential p-scan: one block per batch element ----------------
__global__ __launch_bounds__(1024) void scan_kernel(
    float* __restrict__ Hbuf,
    const float* __restrict__ GHp,        // (4608,900) = Hin@pwh^T + pbh
    const half2_t* __restrict__ pwiH,     // (150,900) f16 pairs
    const float* __restrict__ pwhT,       // (300,900) fp32 (init only)
    const float* __restrict__ pbi,        // (900)
    const float* __restrict__ pbh,        // (900)
    const float* __restrict__ wk,         // (300)
    const float* __restrict__ qd,         // (4608), includes +gb
    const float* __restrict__ adj,        // (48,96,96)
    float* __restrict__ Mbuf,             // (4608,300)
    int ccol, int hcol, int pcol)
{
    int b = blockIdx.x;
    int t = threadIdx.x;

    __shared__ __align__(16) half2_t P_h2[NN][PP];   // 57600 B, P rows f16-paired
    __shared__ __align__(16) float g_s[G3];          // 3600
    __shared__ __align__(16) float Mpart[3][DD];     // 3600
    __shared__ __align__(16) half2_t M_h2[PP];       // 600
    __shared__ __align__(16) float e_s[NN];          // 384
    __shared__ __align__(16) float pk_s[NN];         // 384
    __shared__ __align__(16) float pw_s[DD];         // 1200
    __shared__ __align__(16) float adj_s[NN*NN];     // 36864
    __shared__ __align__(16) float qd_s[NN];         // 384
    __shared__ __align__(16) float ghp_s[G3];        // 3600
    __shared__ __align__(16) float hv_s[DD];         // 1200

    size_t rowbase = (size_t)b*NN;

    // ---- stage adj block + qd for this b
    for (int k=t; k<NN*NN; k+=1024) adj_s[k] = adj[rowbase*NN + k];
    if (t < NN) qd_s[t] = qd[rowbase + t];

    // ---- init (i=0): p0 = GRU(x=0, h=Cin0), M[b,0]=0
    if (t < DD) Mpart[0][t] = Hbuf[rowbase*HDIM + ccol + t];   // Cin0
    __syncthreads();
    if (t < G3){
        float acc = pbh[t];
        #pragma unroll 4
        for (int d=0; d<DD; d++) acc += Mpart[0][d]*pwhT[(size_t)d*G3+t];
        g_s[t] = acc;                                          // gh0
    }
    __syncthreads();
    if (t < PP){
        int d0 = 2*t, d1 = 2*t+1;
        float r0  = sigm(pbi[d0]      + g_s[d0]);
        float z0  = sigm(pbi[DD+d0]   + g_s[DD+d0]);
        float n0  = tanhf(pbi[2*DD+d0] + r0*g_s[2*DD+d0]);
        float p0  = (1.f-z0)*n0 + z0*Mpart[0][d0];
        float r1  = sigm(pbi[d1]      + g_s[d1]);
        float z1  = sigm(pbi[DD+d1]   + g_s[DD+d1]);
        float n1  = tanhf(pbi[2*DD+d1] + r1*g_s[2*DD+d1]);
        float p1  = (1.f-z1)*n1 + z1*Mpart[0][d1];
        *(float2*)&Hbuf[rowbase*HDIM + pcol + d0] = make_float2(p0,p1);
        half2_t ph; ph.x = (_Float16)p0; ph.y = (_Float16)p1;
        P_h2[0][t] = ph;
        pw_s[d0] = p0*wk[d0];
        pw_s[d1] = p1*wk[d1];
        *(float2*)&Mbuf[rowbase*DD + d0] = make_float2(0.f,0.f);  // M[b,0]=0
    }
    __syncthreads();

    for (int i=1;i<NN;i++){
        size_t row = rowbase + i;
        // ---- AB (wave 0): pk reduce + logits + softmax
        if (t < 64){
            float s = 0.f;
            for (int c=t;c<DD;c+=64) s += pw_s[c];
            #pragma unroll
            for (int o=32;o>0;o>>=1) s += __shfl_xor(s,o);
            if (t==0) pk_s[i-1] = s;
            float q = qd_s[i];
            float a0 = NEGI, a1 = NEGI;
            if (t < i){
                if (adj_s[i*NN+t] != 0.f) a0 = q + ((t==i-1)? s : pk_s[t]);
            }
            int j1 = 64+t;
            if (t < 32 && j1 < i){
                if (adj_s[i*NN+j1] != 0.f) a1 = q + ((j1==i-1)? s : pk_s[j1]);
            }
            float m = fmaxf(a0,a1);
            #pragma unroll
            for (int o=32;o>0;o>>=1) m = fmaxf(m, __shfl_xor(m,o));
            float e0 = expf(a0-m);
            float e1 = (t<32)? expf(a1-m) : 0.f;
            float ss = e0+e1;
            #pragma unroll
            for (int o=32;o>0;o>>=1) ss += __shfl_xor(ss,o);
            float inv = 1.f/ss;
            e_s[t] = e0*inv;
            if (t<32) e_s[64+t] = e1*inv;
        }
        __syncthreads();
        // ---- C (t<450): 3-way split weighted sum of LDS P rows; prefetchers (t>=512)
        if (t < 450){
            int g = t/150, dp = t%150;
            int cnt = (i+2)/3;
            int j0 = g*cnt; int j1 = j0+cnt; if (j1 > i) j1 = i;
            float m0=0.f, m1=0.f;
            for (int j=j0;j<j1;j++){
                float w = e_s[j];
                half2_t pv = P_h2[j][dp];
                m0 += w*(float)pv.x;
                m1 += w*(float)pv.y;
            }
            *(float2*)&Mpart[g][2*dp] = make_float2(m0,m1);
        } else if (t >= 512){
            // prefetch GHp row + Hin row for phase E
            int k = t-512;
            #pragma unroll
            for (int it=0; it<2; it++){
                int idx = k + it*512;
                if (idx < 450){
                    *(float2*)&ghp_s[2*idx] = *(const float2*)&GHp[row*G3 + 2*idx];
                } else if (idx < 600){
                    int h = idx-450;
                    *(float2*)&hv_s[2*h] = *(const float2*)&Hbuf[row*HDIM + hcol + 2*h];
                }
            }
        }
        __syncthreads();
        // ---- Csum (t<150): combine partials, write Mbuf + f16 M
        if (t < PP){
            float m0 = Mpart[0][2*t] + Mpart[1][2*t] + Mpart[2][2*t];
            float m1 = Mpart[0][2*t+1] + Mpart[1][2*t+1] + Mpart[2][2*t+1];
            half2_t mh; mh.x = (_Float16)m0; mh.y = (_Float16)m1;
            M_h2[t] = mh;
            *(float2*)&Mbuf[row*DD + 2*t] = make_float2(m0,m1);
        }
        __syncthreads();
        // ---- D (t<900): g = M @ pwi^T + pbi via v_dot2_f32_f16
        if (t < G3){
            float acc0 = 0.f, acc1 = 0.f;
            const half2_t* W = pwiH + t;
            #pragma unroll 10
            for (int p=0;p<PP;p+=2){
                acc0 = __builtin_amdgcn_fdot2(W[(size_t)p*G3],     M_h2[p],   acc0, false);
                acc1 = __builtin_amdgcn_fdot2(W[(size_t)(p+1)*G3], M_h2[p+1], acc1, false);
            }
            g_s[t] = pbi[t] + acc0 + acc1;
        }
        __syncthreads();
        // ---- E (t<150): GRU combine (pure LDS), write P row + pw
        if (t < PP){
            int d0 = 2*t, d1 = 2*t+1;
            float2 hv = *(const float2*)&hv_s[d0];
            float2 wk2 = *(const float2*)&wk[d0];
            float r0  = sigm(g_s[d0]      + ghp_s[d0]);
            float z0  = sigm(g_s[DD+d0]   + ghp_s[DD+d0]);
            float n0  = tanhf(g_s[2*DD+d0] + r0*ghp_s[2*DD+d0]);
            float p0  = (1.f-z0)*n0 + z0*hv.x;
            float r1  = sigm(g_s[d1]      + ghp_s[d1]);
            float z1  = sigm(g_s[DD+d1]   + ghp_s[DD+d1]);
            float n1  = tanhf(g_s[2*DD+d1] + r1*ghp_s[2*DD+d1]);
            float p1  = (1.f-z1)*n1 + z1*hv.y;
            *(float2*)&Hbuf[row*HDIM + pcol + d0] = make_float2(p0,p1);
            half2_t ph; ph.x = (_Float16)p0; ph.y = (_Float16)p1;
            P_h2[i][t] = ph;
            pw_s[d0] = p0*wk2.x;
            pw_s[d1] = p1*wk2.y;
        }
        __syncthreads();
    }
}

// ---------------- c-side elementwise combine: CL = GRU(GIc, GHc, h=M) ----------------
__global__ __launch_bounds__(320) void combine_c(
    const float* __restrict__ GIc, const float* __restrict__ GHc,
    const float* __restrict__ Mbuf, float* __restrict__ Hbuf, int clcol)
{
    size_t row = blockIdx.x;
    int d = threadIdx.x;
    if (d < DD){
        float ir = GIc[row*G3+d], iz = GIc[row*G3+DD+d], inn = GIc[row*G3+2*DD+d];
        float hr = GHc[row*G3+d], hz = GHc[row*G3+DD+d], hn  = GHc[row*G3+2*DD+d];
        float r  = sigm(ir+hr);
        float z  = sigm(iz+hz);
        float nn = tanhf(inn + r*hn);
        float h  = Mbuf[row*DD+d];
        Hbuf[row*HDIM + clcol + d] = (1.f-z)*nn + z*h;
    }
}

// ---------------- logits: out = x2 @ w2 + b2 (N=7) ----------------
__global__ __launch_bounds__(64) void logits_kernel(
    const float* __restrict__ x2, const float* __restrict__ w2,
    const float* __restrict__ b2, float* __restrict__ out)
{
    size_t row = blockIdx.x;
    int lane = threadIdx.x;
    float acc[7]={0,0,0,0,0,0,0};
    for (int d=lane; d<DD; d+=64){
        float x = x2[row*DD+d];
        #pragma unroll
        for (int c=0;c<7;c++) acc[c] += x*w2[d*7+c];
    }
    #pragma unroll
    for (int c=0;c<7;c++){
        float s = acc[c];
        #pragma unroll
        for (int o=32;o>0;o>>=1) s += __shfl_down(s,o);
        if (lane==0) out[row*7+c] = s + b2[c];
    }
}

extern "C" void kernel_launch(void* const* d_in, const int* in_sizes, int n_in,
                              void* d_out, int out_size, void* d_ws, size_t ws_size,
                              hipStream_t stream)
{
    const float* features = (const float*)d_in[0];
    const float* adj      = (const float*)d_in[1];
    const float* fc1_w    = (const float*)d_in[3];
    const float* fc1_b    = (const float*)d_in[4];
    const float* gc_wih   = (const float*)d_in[5];
    const float* gc_whh   = (const float*)d_in[6];
    const float* gc_bih   = (const float*)d_in[7];
    const float* gc_bhh   = (const float*)d_in[8];
    const float* gp_wih   = (const float*)d_in[9];
    const float* gp_whh   = (const float*)d_in[10];
    const float* gp_bih   = (const float*)d_in[11];
    const float* gp_bhh   = (const float*)d_in[12];
    const float* gat_wq   = (const float*)d_in[13];
    const float* gat_wk   = (const float*)d_in[14];
    const float* gat_b    = (const float*)d_in[15];
    const float* mlp_w0   = (const float*)d_in[16];
    const float* mlp_b0   = (const float*)d_in[17];
    const float* mlp_w1   = (const float*)d_in[18];
    const float* mlp_b1   = (const float*)d_in[19];
    const float* mlp_w2   = (const float*)d_in[20];
    const float* mlp_b2   = (const float*)d_in[21];
    float* out = (float*)d_out;

    float* ws = (float*)d_ws;
    size_t off = 0;
    float* Hbuf = ws + off; off += (size_t)ROWS*HDIM;
    float* bufA = ws + off; off += (size_t)ROWS*G3;    // GHp
    float* bufB = ws + off; off += (size_t)ROWS*G3;    // GIc / x1
    float* bufC = ws + off; off += (size_t)ROWS*G3;    // GHc / x2
    float* Mbuf = ws + off; off += (size_t)ROWS*DD;
    float* qd   = ws + off; off += ROWS;
    float* wT   = ws + off; off += (size_t)16*DD*G3;
    half2_t* pwiH = (half2_t*)(ws + off); off += (size_t)LL*PP*G3;
    (void)ws_size; (void)in_sizes; (void)n_in; (void)out_size;

    // 1. transpose GRU weights (fp32) + pack pwi to f16 pairs
    {
        dim3 g((G3+31)/32, (DD+31)/32, 16);
        dim3 bl(32,8);
        transpose_w<<<g, bl, 0, stream>>>(gc_wih, gc_whh, gp_wih, gp_whh, wT);
        pack_pwi<<<dim3((PP*G3+255)/256, LL), 256, 0, stream>>>(gp_wih, pwiH);
    }
    // 2. H0 = relu(features @ fc1_w + fc1_b) -> Hbuf col 0
    gemm_kernel<64,4><<<dim3(5,36),256,0,stream>>>(features, EE, fc1_w, DD, fc1_b,
                                                   Hbuf, HDIM, ROWS, DD, EE, 1);
    // 3. features -> Hbuf cols [2700,3724)
    featcopy<<<ROWS,256,0,stream>>>(features, Hbuf);

    for (int l=0;l<LL;l++){
        int ccol  = (l==0)? 0 : 300 + (l-1)*600;
        int hcol  = l*300;
        int pcol  = 600 + l*600;
        int clcol = 300 + l*600;
        const float* cwiT = wT + (size_t)(l*4+0)*DD*G3;
        const float* cwhT = wT + (size_t)(l*4+1)*DD*G3;
        const float* pwhT = wT + (size_t)(l*4+3)*DD*G3;
        const half2_t* pwiHl = pwiH + (size_t)l*PP*G3;

        // GHp = Hin @ pwh^T + pbh
        gemm_kernel<128,8><<<dim3(8,36),256,0,stream>>>(Hbuf+hcol, HDIM, pwhT, G3,
                                                        gp_bhh + l*G3, bufA, G3,
                                                        ROWS, G3, DD, 0);
        // qdot = Cin·wq + gb
        qdot_kernel<<<1152,256,0,stream>>>(Hbuf, ccol, gat_wq + l*DD, gat_b, l, qd);
        // sequential p-scan
        scan_kernel<<<BB,1024,0,stream>>>(Hbuf, bufA, pwiHl, pwhT,
                                          gp_bih + l*G3, gp_bhh + l*G3,
                                          gat_wk + l*DD, qd, adj, Mbuf,
                                          ccol, hcol, pcol);
        // GIc = Cin @ cwi^T + cbi
        gemm_kernel<128,8><<<dim3(8,36),256,0,stream>>>(Hbuf+ccol, HDIM, cwiT, G3,
                                                        gc_bih + l*G3, bufB, G3,
                                                        ROWS, G3, DD, 0);
        // GHc = M @ cwh^T + cbh
        gemm_kernel<128,8><<<dim3(8,36),256,0,stream>>>(Mbuf, DD, cwhT, G3,
                                                        gc_bhh + l*G3, bufC, G3,
                                                        ROWS, G3, DD, 0);
        // CL = GRU-combine
        combine_c<<<ROWS,320,0,stream>>>(bufB, bufC, Mbuf, Hbuf, clcol);
    }

    // MLP
    gemm_kernel<64,4><<<dim3(5,36),256,0,stream>>>(Hbuf, HDIM, mlp_w0, DD, mlp_b0,
                                                   bufB, DD, ROWS, DD, HDIM, 1);
    gemm_kernel<64,4><<<dim3(5,36),256,0,stream>>>(bufB, DD, mlp_w1, DD, mlp_b1,
                                                   bufC, DD, ROWS, DD, DD, 1);
    logits_kernel<<<ROWS,64,0,stream>>>(bufC, mlp_w2, mlp_b2, out);
}

// Round 4
// 3946.286 us; speedup vs baseline: 1.9493x; 1.2732x over previous
//
#include <hip/hip_runtime.h>
#include <math.h>

#define BB 48
#define NN 96
#define EE 1024
#define DD 300
#define LL 4
#define G3 900          // 3*D
#define PP 150          // DD/2 packed f16 pairs
#define HDIM 3724       // D*(2L+1)+E
#define ROWS (BB*NN)    // 4608
#define NEGI -1.0e30f
#define KP300 304       // 300 padded to mult-of-8

typedef _Float16 half2_t __attribute__((ext_vector_type(2)));
typedef _Float16 h8 __attribute__((ext_vector_type(8)));
typedef float f4 __attribute__((ext_vector_type(4)));

__device__ __forceinline__ float sigm(float x){ return 1.0f/(1.0f+expf(-x)); }

// ---------------- transpose pwh (900,300) -> pwhT (300,900), fp32, scan-init only ----------------
__global__ void transpose_w(const float* __restrict__ gp_whh, float* __restrict__ wT)
{
    __shared__ float tile[32][33];
    int l = blockIdx.z;
    const float* src = gp_whh + (size_t)l*G3*DD;
    float* dst = wT + (size_t)l*DD*G3;
    int g0 = blockIdx.x*32;        // along 900
    int d0 = blockIdx.y*32;        // along 300
    int tx = threadIdx.x, ty = threadIdx.y;   // (32,8)
    #pragma unroll
    for (int r=0;r<32;r+=8){
        int g = g0+ty+r, d = d0+tx;
        tile[ty+r][tx] = (g<G3 && d<DD) ? src[(size_t)g*DD+d] : 0.f;
    }
    __syncthreads();
    #pragma unroll
    for (int r=0;r<32;r+=8){
        int d = d0+ty+r, g = g0+tx;
        if (d<DD && g<G3) dst[(size_t)d*G3+g] = tile[tx][ty+r];
    }
}

// ---------------- pack pwi (L,900,300) -> f16-pair layout (L,150,900) for scan ----------------
__global__ __launch_bounds__(256) void pack_pwi(const float* __restrict__ gp_wih,
                                                half2_t* __restrict__ pwiH)
{
    int l = blockIdx.y;
    int idx = blockIdx.x*256 + threadIdx.x;
    if (idx >= PP*G3) return;
    int p = idx / G3, g = idx % G3;
    const float* src = gp_wih + (size_t)l*G3*DD + (size_t)g*DD + 2*p;
    half2_t h;
    h.x = (_Float16)src[0];
    h.y = (_Float16)src[1];
    pwiH[(size_t)l*PP*G3 + idx] = h;
}

// ---------------- GRU weights [900][300] fp32 -> [900][304] f16 (zero-padded) ----------------
// z = l*3 + {0:pwh, 1:cwi, 2:cwh}
__global__ __launch_bounds__(256) void conv_gru_w(const float* __restrict__ gp_whh,
                                                  const float* __restrict__ gc_wih,
                                                  const float* __restrict__ gc_whh,
                                                  _Float16* __restrict__ outp)
{
    int z = blockIdx.y; int l = z/3, wsel = z%3;
    const float* src = (wsel==0?gp_whh:wsel==1?gc_wih:gc_whh) + (size_t)l*G3*DD;
    _Float16* dst = outp + (size_t)z*G3*KP300;
    int idx = blockIdx.x*256 + threadIdx.x;
    if (idx >= G3*KP300) return;
    int n = idx/KP300, k = idx%KP300;
    dst[idx] = (k<DD) ? (_Float16)src[(size_t)n*DD+k] : (_Float16)0.f;
}

// ---------------- transpose-convert [K][N] fp32 -> [N][Kpad] f16 ----------------
__global__ __launch_bounds__(256) void convT(const float* __restrict__ src,
                                             _Float16* __restrict__ dst,
                                             int K, int N, int Kpad)
{
    int idx = blockIdx.x*256 + threadIdx.x;
    if (idx >= N*Kpad) return;
    int n = idx/Kpad, k = idx%Kpad;
    dst[idx] = (k<K) ? (_Float16)src[(size_t)k*N + n] : (_Float16)0.f;
}

// ---------------- MFMA f16 GEMM: C(M x N) = act(A_f32 * B^T + bias) ----------------
// A: fp32 [M][K], row stride lda (16B-aligned rows). M mult of 128.
// B: f16 [N][Kpad] row-major (weights), zero-padded to Kpad (mult of 8).
// C: fp32, row stride ldc. bias[N]. Tiles: BM=128, BN=64, BK=32; 256 threads / 4 waves.
__global__ __launch_bounds__(256) void gemm_mfma(
    const float* __restrict__ A, int lda,
    const _Float16* __restrict__ B, int Kpad,
    const float* __restrict__ bias,
    float* __restrict__ C, int ldc,
    int N, int K, int relu)
{
    constexpr int BM=128, BN=64, BK=32, KPS=40;  // KPS: padded LDS k-stride
    __shared__ _Float16 As[BM][KPS];
    __shared__ _Float16 Bs[BN][KPS];
    int tid = threadIdx.x;
    int m0 = blockIdx.y*BM, n0 = blockIdx.x*BN;
    int w = tid>>6, lane = tid&63;
    int wy = w>>1, wx = w&1;          // 2x2 waves: 64 rows x 32 cols each
    int lm = lane&15, q = lane>>4;

    f4 acc[4][2];
    #pragma unroll
    for (int a=0;a<4;a++)
        #pragma unroll
        for (int b=0;b<2;b++)
            #pragma unroll
            for (int r=0;r<4;r++) acc[a][b][r]=0.f;

    int am = tid>>1, akg = (tid&1)*16;     // A staging: 2 threads/row
    int bn = tid>>2, bkg = (tid&3)*8;      // B staging: 4 threads/row
    const float* arow = A + (size_t)(m0+am)*lda;

    for (int k0=0; k0<K; k0+=BK){
        // stage A (fp32 -> f16)
        {
            __align__(16) _Float16 av[16];
            #pragma unroll
            for (int u=0;u<16;u+=4){
                int k = k0 + akg + u;
                float x0,x1,x2,x3;
                if (k+4 <= K){
                    float4 v = *(const float4*)(arow + k);
                    x0=v.x;x1=v.y;x2=v.z;x3=v.w;
                } else {
                    x0 = (k  <K)? arow[k  ]:0.f;
                    x1 = (k+1<K)? arow[k+1]:0.f;
                    x2 = (k+2<K)? arow[k+2]:0.f;
                    x3 = (k+3<K)? arow[k+3]:0.f;
                }
                av[u]=(_Float16)x0; av[u+1]=(_Float16)x1;
                av[u+2]=(_Float16)x2; av[u+3]=(_Float16)x3;
            }
            *(h8*)&As[am][akg]   = *(h8*)&av[0];
            *(h8*)&As[am][akg+8] = *(h8*)&av[8];
        }
        // stage B (f16 direct, zero rows beyond N / k beyond Kpad)
        {
            int gk = k0 + bkg;
            h8 bv;
            #pragma unroll
            for (int j=0;j<8;j++) bv[j]=(_Float16)0.f;
            if (n0+bn < N && gk < Kpad)
                bv = *(const h8*)(B + (size_t)(n0+bn)*Kpad + gk);
            *(h8*)&Bs[bn][bkg] = bv;
        }
        __syncthreads();
        h8 af[4], bf[2];
        #pragma unroll
        for (int mb=0; mb<4; mb++) af[mb] = *(h8*)&As[wy*64+mb*16+lm][q*8];
        #pragma unroll
        for (int nb=0; nb<2; nb++) bf[nb] = *(h8*)&Bs[wx*32+nb*16+lm][q*8];
        #pragma unroll
        for (int mb=0; mb<4; mb++)
            #pragma unroll
            for (int nb=0; nb<2; nb++)
                acc[mb][nb] = __builtin_amdgcn_mfma_f32_16x16x32_f16(af[mb], bf[nb], acc[mb][nb], 0,0,0);
        __syncthreads();
    }
    // epilogue: C/D layout col=lane&15, row=q*4+reg
    #pragma unroll
    for (int mb=0; mb<4; mb++){
        int r0 = m0 + wy*64 + mb*16 + q*4;
        #pragma unroll
        for (int nb=0; nb<2; nb++){
            int c = n0 + wx*32 + nb*16 + lm;
            if (c < N){
                float bb = bias[c];
                #pragma unroll
                for (int reg=0; reg<4; reg++){
                    float v = acc[mb][nb][reg] + bb;
                    if (relu) v = fmaxf(v, 0.f);
                    C[(size_t)(r0+reg)*ldc + c] = v;
                }
            }
        }
    }
}

// ---------------- copy features into last 1024 cols of Hbuf ----------------
__global__ void featcopy(const float* __restrict__ f, float* __restrict__ H)
{
    size_t row = blockIdx.x;
    int t = threadIdx.x;
    float4 v = *(const float4*)(f + row*EE + t*4);
    *(float4*)(H + row*HDIM + 2700 + t*4) = v;
}

// ---------------- qdot[r] = Cin[r,:]·wq + gb ----------------
__global__ __launch_bounds__(256) void qdot_kernel(
    const float* __restrict__ Hbuf, int ccol,
    const float* __restrict__ wq, const float* __restrict__ gat_b, int l,
    float* __restrict__ qd)
{
    int row = blockIdx.x*4 + (threadIdx.x>>6);
    int lane = threadIdx.x & 63;
    const float* x = Hbuf + (size_t)row*HDIM + ccol;
    float s = 0.f;
    for (int d=lane; d<DD; d+=64) s += x[d]*wq[d];
    #pragma unroll
    for (int o=32;o>0;o>>=1) s += __shfl_down(s,o);
    if (lane==0) qd[row] = s + gat_b[l];
}

// ---------------- the sequential p-scan: one block per batch element ----------------
__global__ __launch_bounds__(1024) void scan_kernel(
    float* __restrict__ Hbuf,
    const float* __restrict__ GHp,        // (4608,900) = Hin@pwh^T + pbh
    const half2_t* __restrict__ pwiH,     // (150,900) f16 pairs
    const float* __restrict__ pwhT,       // (300,900) fp32 (init only)
    const float* __restrict__ pbi,        // (900)
    const float* __restrict__ pbh,        // (900)
    const float* __restrict__ wk,         // (300)
    const float* __restrict__ qd,         // (4608), includes +gb
    const float* __restrict__ adj,        // (48,96,96)
    float* __restrict__ Mbuf,             // (4608,300)
    int ccol, int hcol, int pcol)
{
    int b = blockIdx.x;
    int t = threadIdx.x;

    __shared__ __align__(16) half2_t P_h2[NN][PP];   // 57600 B
    __shared__ __align__(16) float g_s[G3];
    __shared__ __align__(16) float Mpart[3][DD];
    __shared__ __align__(16) half2_t M_h2[PP];
    __shared__ __align__(16) float e_s[NN];
    __shared__ __align__(16) float pk_s[NN];
    __shared__ __align__(16) float pw_s[DD];
    __shared__ __align__(16) float adj_s[NN*NN];
    __shared__ __align__(16) float qd_s[NN];
    __shared__ __align__(16) float ghp_s[G3];
    __shared__ __align__(16) float hv_s[DD];

    size_t rowbase = (size_t)b*NN;

    for (int k=t; k<NN*NN; k+=1024) adj_s[k] = adj[rowbase*NN + k];
    if (t < NN) qd_s[t] = qd[rowbase + t];

    if (t < DD) Mpart[0][t] = Hbuf[rowbase*HDIM + ccol + t];   // Cin0
    __syncthreads();
    if (t < G3){
        float acc = pbh[t];
        #pragma unroll 4
        for (int d=0; d<DD; d++) acc += Mpart[0][d]*pwhT[(size_t)d*G3+t];
        g_s[t] = acc;
    }
    __syncthreads();
    if (t < PP){
        int d0 = 2*t, d1 = 2*t+1;
        float r0  = sigm(pbi[d0]      + g_s[d0]);
        float z0  = sigm(pbi[DD+d0]   + g_s[DD+d0]);
        float n0  = tanhf(pbi[2*DD+d0] + r0*g_s[2*DD+d0]);
        float p0  = (1.f-z0)*n0 + z0*Mpart[0][d0];
        float r1  = sigm(pbi[d1]      + g_s[d1]);
        float z1  = sigm(pbi[DD+d1]   + g_s[DD+d1]);
        float n1  = tanhf(pbi[2*DD+d1] + r1*g_s[2*DD+d1]);
        float p1  = (1.f-z1)*n1 + z1*Mpart[0][d1];
        *(float2*)&Hbuf[rowbase*HDIM + pcol + d0] = make_float2(p0,p1);
        half2_t ph; ph.x = (_Float16)p0; ph.y = (_Float16)p1;
        P_h2[0][t] = ph;
        pw_s[d0] = p0*wk[d0];
        pw_s[d1] = p1*wk[d1];
        *(float2*)&Mbuf[rowbase*DD + d0] = make_float2(0.f,0.f);
    }
    __syncthreads();

    for (int i=1;i<NN;i++){
        size_t row = rowbase + i;
        if (t < 64){
            float s = 0.f;
            for (int c=t;c<DD;c+=64) s += pw_s[c];
            #pragma unroll
            for (int o=32;o>0;o>>=1) s += __shfl_xor(s,o);
            if (t==0) pk_s[i-1] = s;
            float q = qd_s[i];
            float a0 = NEGI, a1 = NEGI;
            if (t < i){
                if (adj_s[i*NN+t] != 0.f) a0 = q + ((t==i-1)? s : pk_s[t]);
            }
            int j1 = 64+t;
            if (t < 32 && j1 < i){
                if (adj_s[i*NN+j1] != 0.f) a1 = q + ((j1==i-1)? s : pk_s[j1]);
            }
            float m = fmaxf(a0,a1);
            #pragma unroll
            for (int o=32;o>0;o>>=1) m = fmaxf(m, __shfl_xor(m,o));
            float e0 = expf(a0-m);
            float e1 = (t<32)? expf(a1-m) : 0.f;
            float ss = e0+e1;
            #pragma unroll
            for (int o=32;o>0;o>>=1) ss += __shfl_xor(ss,o);
            float inv = 1.f/ss;
            e_s[t] = e0*inv;
            if (t<32) e_s[64+t] = e1*inv;
        }
        __syncthreads();
        if (t < 450){
            int g = t/150, dp = t%150;
            int cnt = (i+2)/3;
            int j0 = g*cnt; int j1 = j0+cnt; if (j1 > i) j1 = i;
            float m0=0.f, m1=0.f;
            for (int j=j0;j<j1;j++){
                float w = e_s[j];
                half2_t pv = P_h2[j][dp];
                m0 += w*(float)pv.x;
                m1 += w*(float)pv.y;
            }
            *(float2*)&Mpart[g][2*dp] = make_float2(m0,m1);
        } else if (t >= 512){
            int k = t-512;
            #pragma unroll
            for (int it=0; it<2; it++){
                int idx = k + it*512;
                if (idx < 450){
                    *(float2*)&ghp_s[2*idx] = *(const float2*)&GHp[row*G3 + 2*idx];
                } else if (idx < 600){
                    int h = idx-450;
                    *(float2*)&hv_s[2*h] = *(const float2*)&Hbuf[row*HDIM + hcol + 2*h];
                }
            }
        }
        __syncthreads();
        if (t < PP){
            float m0 = Mpart[0][2*t] + Mpart[1][2*t] + Mpart[2][2*t];
            float m1 = Mpart[0][2*t+1] + Mpart[1][2*t+1] + Mpart[2][2*t+1];
            half2_t mh; mh.x = (_Float16)m0; mh.y = (_Float16)m1;
            M_h2[t] = mh;
            *(float2*)&Mbuf[row*DD + 2*t] = make_float2(m0,m1);
        }
        __syncthreads();
        if (t < G3){
            float acc0 = 0.f, acc1 = 0.f;
            const half2_t* W = pwiH + t;
            #pragma unroll 10
            for (int p=0;p<PP;p+=2){
                acc0 = __builtin_amdgcn_fdot2(W[(size_t)p*G3],     M_h2[p],   acc0, false);
                acc1 = __builtin_amdgcn_fdot2(W[(size_t)(p+1)*G3], M_h2[p+1], acc1, false);
            }
            g_s[t] = pbi[t] + acc0 + acc1;
        }
        __syncthreads();
        if (t < PP){
            int d0 = 2*t, d1 = 2*t+1;
            float2 hv = *(const float2*)&hv_s[d0];
            float2 wk2 = *(const float2*)&wk[d0];
            float r0  = sigm(g_s[d0]      + ghp_s[d0]);
            float z0  = sigm(g_s[DD+d0]   + ghp_s[DD+d0]);
            float n0  = tanhf(g_s[2*DD+d0] + r0*ghp_s[2*DD+d0]);
            float p0  = (1.f-z0)*n0 + z0*hv.x;
            float r1  = sigm(g_s[d1]      + ghp_s[d1]);
            float z1  = sigm(g_s[DD+d1]   + ghp_s[DD+d1]);
            float n1  = tanhf(g_s[2*DD+d1] + r1*ghp_s[2*DD+d1]);
            float p1  = (1.f-z1)*n1 + z1*hv.y;
            *(float2*)&Hbuf[row*HDIM + pcol + d0] = make_float2(p0,p1);
            half2_t ph; ph.x = (_Float16)p0; ph.y = (_Float16)p1;
            P_h2[i][t] = ph;
            pw_s[d0] = p0*wk2.x;
            pw_s[d1] = p1*wk2.y;
        }
        __syncthreads();
    }
}

// ---------------- c-side elementwise combine ----------------
__global__ __launch_bounds__(320) void combine_c(
    const float* __restrict__ GIc, const float* __restrict__ GHc,
    const float* __restrict__ Mbuf, float* __restrict__ Hbuf, int clcol)
{
    size_t row = blockIdx.x;
    int d = threadIdx.x;
    if (d < DD){
        float ir = GIc[row*G3+d], iz = GIc[row*G3+DD+d], inn = GIc[row*G3+2*DD+d];
        float hr = GHc[row*G3+d], hz = GHc[row*G3+DD+d], hn  = GHc[row*G3+2*DD+d];
        float r  = sigm(ir+hr);
        float z  = sigm(iz+hz);
        float nn = tanhf(inn + r*hn);
        float h  = Mbuf[row*DD+d];
        Hbuf[row*HDIM + clcol + d] = (1.f-z)*nn + z*h;
    }
}

// ---------------- logits: out = x2 @ w2 + b2 (N=7) ----------------
__global__ __launch_bounds__(64) void logits_kernel(
    const float* __restrict__ x2, const float* __restrict__ w2,
    const float* __restrict__ b2, float* __restrict__ out)
{
    size_t row = blockIdx.x;
    int lane = threadIdx.x;
    float acc[7]={0,0,0,0,0,0,0};
    for (int d=lane; d<DD; d+=64){
        float x = x2[row*DD+d];
        #pragma unroll
        for (int c=0;c<7;c++) acc[c] += x*w2[d*7+c];
    }
    #pragma unroll
    for (int c=0;c<7;c++){
        float s = acc[c];
        #pragma unroll
        for (int o=32;o>0;o>>=1) s += __shfl_down(s,o);
        if (lane==0) out[row*7+c] = s + b2[c];
    }
}

extern "C" void kernel_launch(void* const* d_in, const int* in_sizes, int n_in,
                              void* d_out, int out_size, void* d_ws, size_t ws_size,
                              hipStream_t stream)
{
    const float* features = (const float*)d_in[0];
    const float* adj      = (const float*)d_in[1];
    const float* fc1_w    = (const float*)d_in[3];
    const float* fc1_b    = (const float*)d_in[4];
    const float* gc_wih   = (const float*)d_in[5];
    const float* gc_whh   = (const float*)d_in[6];
    const float* gc_bih   = (const float*)d_in[7];
    const float* gc_bhh   = (const float*)d_in[8];
    const float* gp_wih   = (const float*)d_in[9];
    const float* gp_whh   = (const float*)d_in[10];
    const float* gp_bih   = (const float*)d_in[11];
    const float* gp_bhh   = (const float*)d_in[12];
    const float* gat_wq   = (const float*)d_in[13];
    const float* gat_wk   = (const float*)d_in[14];
    const float* gat_b    = (const float*)d_in[15];
    const float* mlp_w0   = (const float*)d_in[16];
    const float* mlp_b0   = (const float*)d_in[17];
    const float* mlp_w1   = (const float*)d_in[18];
    const float* mlp_b1   = (const float*)d_in[19];
    const float* mlp_w2   = (const float*)d_in[20];
    const float* mlp_b2   = (const float*)d_in[21];
    float* out = (float*)d_out;

    float* ws = (float*)d_ws;
    size_t off = 0;
    float* Hbuf = ws + off; off += (size_t)ROWS*HDIM;
    float* bufA = ws + off; off += (size_t)ROWS*G3;    // GHp
    float* bufB = ws + off; off += (size_t)ROWS*G3;    // GIc / x1
    float* bufC = ws + off; off += (size_t)ROWS*G3;    // GHc / x2
    float* Mbuf = ws + off; off += (size_t)ROWS*DD;
    float* qd   = ws + off; off += ROWS;
    float* wT   = ws + off; off += (size_t)LL*DD*G3;               // pwhT fp32 (scan init)
    half2_t* pwiH = (half2_t*)(ws + off); off += (size_t)LL*PP*G3; // scan weights
    _Float16* gruF = (_Float16*)(ws + off); off += (size_t)12*G3*KP300/2;  // 12x [900][304] f16
    _Float16* fc1F = (_Float16*)(ws + off); off += (size_t)DD*EE/2;        // [300][1024]
    _Float16* mlp0F= (_Float16*)(ws + off); off += (size_t)DD*3728/2;      // [300][3728]
    _Float16* mlp1F= (_Float16*)(ws + off); off += (size_t)DD*KP300/2;     // [300][304]
    (void)ws_size; (void)in_sizes; (void)n_in; (void)out_size;

    // 1. weight prep (runs every call; cheap)
    {
        dim3 g((G3+31)/32, (DD+31)/32, LL);
        dim3 bl(32,8);
        transpose_w<<<g, bl, 0, stream>>>(gp_whh, wT);
        pack_pwi<<<dim3((PP*G3+255)/256, LL), 256, 0, stream>>>(gp_wih, pwiH);
        conv_gru_w<<<dim3((G3*KP300+255)/256, 12), 256, 0, stream>>>(gp_whh, gc_wih, gc_whh, gruF);
        convT<<<(DD*EE+255)/256, 256, 0, stream>>>(fc1_w, fc1F, EE, DD, EE);
        convT<<<(DD*3728+255)/256, 256, 0, stream>>>(mlp_w0, mlp0F, HDIM, DD, 3728);
        convT<<<(DD*KP300+255)/256, 256, 0, stream>>>(mlp_w1, mlp1F, DD, DD, KP300);
    }
    // 2. H0 = relu(features @ fc1_w + fc1_b) -> Hbuf col 0
    gemm_mfma<<<dim3(5,36),256,0,stream>>>(features, EE, fc1F, EE, fc1_b,
                                           Hbuf, HDIM, DD, EE, 1);
    // 3. features -> Hbuf cols [2700,3724)
    featcopy<<<ROWS,256,0,stream>>>(features, Hbuf);

    for (int l=0;l<LL;l++){
        int ccol  = (l==0)? 0 : 300 + (l-1)*600;
        int hcol  = l*300;
        int pcol  = 600 + l*600;
        int clcol = 300 + l*600;
        const float* pwhT = wT + (size_t)l*DD*G3;
        const half2_t* pwiHl = pwiH + (size_t)l*PP*G3;
        const _Float16* pwhF = gruF + (size_t)(l*3+0)*G3*KP300;
        const _Float16* cwiF = gruF + (size_t)(l*3+1)*G3*KP300;
        const _Float16* cwhF = gruF + (size_t)(l*3+2)*G3*KP300;

        // GHp = Hin @ pwh^T + pbh
        gemm_mfma<<<dim3(15,36),256,0,stream>>>(Hbuf+hcol, HDIM, pwhF, KP300,
                                                gp_bhh + l*G3, bufA, G3, G3, DD, 0);
        // qdot = Cin·wq + gb
        qdot_kernel<<<1152,256,0,stream>>>(Hbuf, ccol, gat_wq + l*DD, gat_b, l, qd);
        // sequential p-scan
        scan_kernel<<<BB,1024,0,stream>>>(Hbuf, bufA, pwiHl, pwhT,
                                          gp_bih + l*G3, gp_bhh + l*G3,
                                          gat_wk + l*DD, qd, adj, Mbuf,
                                          ccol, hcol, pcol);
        // GIc = Cin @ cwi^T + cbi
        gemm_mfma<<<dim3(15,36),256,0,stream>>>(Hbuf+ccol, HDIM, cwiF, KP300,
                                                gc_bih + l*G3, bufB, G3, G3, DD, 0);
        // GHc = M @ cwh^T + cbh
        gemm_mfma<<<dim3(15,36),256,0,stream>>>(Mbuf, DD, cwhF, KP300,
                                                gc_bhh + l*G3, bufC, G3, G3, DD, 0);
        // CL = GRU-combine
        combine_c<<<ROWS,320,0,stream>>>(bufB, bufC, Mbuf, Hbuf, clcol);
    }

    // MLP
    gemm_mfma<<<dim3(5,36),256,0,stream>>>(Hbuf, HDIM, mlp0F, 3728, mlp_b0,
                                           bufB, DD, DD, HDIM, 1);
    gemm_mfma<<<dim3(5,36),256,0,stream>>>(bufB, DD, mlp1F, KP300, mlp_b1,
                                           bufC, DD, DD, DD, 1);
    logits_kernel<<<ROWS,64,0,stream>>>(bufC, mlp_w2, mlp_b2, out);
}